// Round 1
// baseline (936.944 us; speedup 1.0000x reference)
//
#include <hip/hip_runtime.h>
#include <hip/hip_bf16.h>
#include <math.h>

// Problem constants (from reference)
#define BATCH 4
#define SEQL 256          // L = C = 256
#define DMODEL 1024
#define DINNER 2048
#define DSTATE 16
#define DTRANK 64
#define OUTC 1024
#define NROWS (BATCH * SEQL)   // 1024

// ---------------------------------------------------------------------------
// Generic fp32 tiled GEMM: C[m,n] = sum_k X[m*K+k] * W[n*K+k]
// X: (M,K) row-major, W: (N,K) row-major (i.e. C = X @ W^T)
// BM=BN=64, BK=16, block 256 threads, 4x4 microtile per thread.
// All our M,N divisible by 64 and K divisible by 16 -> no guards.
// ---------------------------------------------------------------------------
__global__ __launch_bounds__(256) void gemm_xwt(const float* __restrict__ X,
                                                const float* __restrict__ W,
                                                float* __restrict__ C,
                                                int M, int N, int K) {
    const int BM = 64, BN = 64, BK = 16;
    __shared__ float As[BK][BM + 1];
    __shared__ float Bs[BK][BN + 1];
    const int t  = threadIdx.x;
    const int tx = t % 16;          // n-direction
    const int ty = t / 16;          // m-direction
    const int m0 = blockIdx.y * BM;
    const int n0 = blockIdx.x * BN;
    float acc[4][4] = {};
    for (int k0 = 0; k0 < K; k0 += BK) {
        // Stage A tile (64x16) and B tile (64x16), 4 elems per thread each
        #pragma unroll
        for (int i = t; i < BM * BK; i += 256) {
            int r = i / BK, c = i % BK;
            As[c][r] = X[(size_t)(m0 + r) * K + k0 + c];
        }
        #pragma unroll
        for (int i = t; i < BN * BK; i += 256) {
            int r = i / BK, c = i % BK;
            Bs[c][r] = W[(size_t)(n0 + r) * K + k0 + c];
        }
        __syncthreads();
        #pragma unroll
        for (int kk = 0; kk < BK; ++kk) {
            float a[4], b[4];
            #pragma unroll
            for (int i = 0; i < 4; ++i) a[i] = As[kk][ty * 4 + i];
            #pragma unroll
            for (int j = 0; j < 4; ++j) b[j] = Bs[kk][tx * 4 + j];
            #pragma unroll
            for (int i = 0; i < 4; ++i)
                #pragma unroll
                for (int j = 0; j < 4; ++j)
                    acc[i][j] += a[i] * b[j];
        }
        __syncthreads();
    }
    #pragma unroll
    for (int i = 0; i < 4; ++i)
        #pragma unroll
        for (int j = 0; j < 4; ++j)
            C[(size_t)(m0 + ty * 4 + i) * N + n0 + tx * 4 + j] = acc[i][j];
}

// ---------------------------------------------------------------------------
// Depthwise causal conv1d (k=4, left pad 3) + bias + SiLU.
// Input: xz (NROWS, 2*DINNER), uses xs half = xz[..., 0:DINNER].
// Output: xs (NROWS, DINNER)
// ---------------------------------------------------------------------------
__global__ void conv_silu_kernel(const float* __restrict__ xz,
                                 const float* __restrict__ conv_w,
                                 const float* __restrict__ conv_b,
                                 float* __restrict__ xs) {
    int idx = blockIdx.x * blockDim.x + threadIdx.x;  // (b*L + l)*DINNER + d
    int d = idx & (DINNER - 1);
    int l = (idx >> 11) & (SEQL - 1);
    int b = idx >> 19;
    const float w0 = conv_w[d * 4 + 0];
    const float w1 = conv_w[d * 4 + 1];
    const float w2 = conv_w[d * 4 + 2];
    const float w3 = conv_w[d * 4 + 3];
    float acc = conv_b[d];
    const size_t base = (size_t)(b * SEQL) * (2 * DINNER) + d;
    if (l >= 3) acc += w0 * xz[base + (size_t)(l - 3) * (2 * DINNER)];
    if (l >= 2) acc += w1 * xz[base + (size_t)(l - 2) * (2 * DINNER)];
    if (l >= 1) acc += w2 * xz[base + (size_t)(l - 1) * (2 * DINNER)];
    acc += w3 * xz[base + (size_t)l * (2 * DINNER)];
    xs[idx] = acc / (1.f + __expf(-acc));
}

// ---------------------------------------------------------------------------
// x_proj: x_dbl[row, e] = sum_d xs[row,d] * x_proj_w[e,d]
// one wave per (row, e); e in [0,96)
// ---------------------------------------------------------------------------
__global__ void xproj_kernel(const float* __restrict__ xs,
                             const float* __restrict__ Wp,
                             float* __restrict__ xdbl) {
    const int row = blockIdx.y;
    const int e = blockIdx.x;
    const int lane = threadIdx.x;  // 0..63
    const float* xr = xs + (size_t)row * DINNER;
    const float* wr = Wp + (size_t)e * DINNER;
    float acc = 0.f;
    #pragma unroll
    for (int k = lane; k < DINNER; k += 64) acc += xr[k] * wr[k];
    #pragma unroll
    for (int o = 32; o; o >>= 1) acc += __shfl_down(acc, o);
    if (lane == 0) xdbl[row * 96 + e] = acc;
}

// ---------------------------------------------------------------------------
// dt_proj + softplus: delta[row,d] = softplus(sum_r dt[row,r]*Wd[d,r] + bd[d])
// block = 256 threads over d, grid = (DINNER/256, NROWS)
// ---------------------------------------------------------------------------
__global__ __launch_bounds__(256) void dtproj_kernel(const float* __restrict__ xdbl,
                                                     const float* __restrict__ Wd,
                                                     const float* __restrict__ bd,
                                                     float* __restrict__ delta) {
    __shared__ float sdt[DTRANK];
    const int row = blockIdx.y;
    const int d = blockIdx.x * 256 + threadIdx.x;
    if (threadIdx.x < DTRANK) sdt[threadIdx.x] = xdbl[row * 96 + threadIdx.x];
    __syncthreads();
    float acc = bd[d];
    const float* w = Wd + (size_t)d * DTRANK;
    #pragma unroll
    for (int r = 0; r < DTRANK; ++r) acc += sdt[r] * w[r];
    float sp = (acc > 20.f) ? acc : log1pf(__expf(acc));
    delta[(size_t)row * DINNER + d] = sp;
}

// ---------------------------------------------------------------------------
// Selective scan, fused with +D*xs and *silu(res).
// thread = (d_local, n): block 256 = 16 d x 16 n. grid (DINNER/16, B).
// h kept in a register; sequential over L=256.
// ---------------------------------------------------------------------------
__global__ __launch_bounds__(256) void scan_kernel(const float* __restrict__ delta,
                                                   const float* __restrict__ xs,
                                                   const float* __restrict__ xdbl,
                                                   const float* __restrict__ xz,
                                                   const float* __restrict__ A_log,
                                                   const float* __restrict__ Dp,
                                                   float* __restrict__ ybuf) {
    const int b = blockIdx.y;
    const int dg = blockIdx.x;          // 0..127
    const int t = threadIdx.x;
    const int dl = t >> 4;              // 0..15
    const int n = t & 15;
    const int d = dg * 16 + dl;
    const float a = -__expf(A_log[d * DSTATE + n]);
    const float Dv = Dp[d];
    float h = 0.f;
    const int rowbase = b * SEQL;
    for (int l = 0; l < SEQL; ++l) {
        const int row = rowbase + l;
        const float dv = delta[(size_t)row * DINNER + d];
        const float xv = xs[(size_t)row * DINNER + d];
        const float bm = xdbl[row * 96 + DTRANK + n];
        const float cm = xdbl[row * 96 + DTRANK + DSTATE + n];
        h = __expf(dv * a) * h + dv * bm * xv;
        float p = h * cm;
        p += __shfl_xor(p, 1);
        p += __shfl_xor(p, 2);
        p += __shfl_xor(p, 4);
        p += __shfl_xor(p, 8);
        if (n == 0) {
            const float r = xz[(size_t)row * (2 * DINNER) + DINNER + d];
            float y = p + Dv * xv;
            y = y * (r / (1.f + __expf(-r)));
            ybuf[(size_t)row * DINNER + d] = y;
        }
    }
}

// ---------------------------------------------------------------------------
// LayerNorm over last dim (1024). block per row, 256 threads x 4 elems.
// ---------------------------------------------------------------------------
__global__ __launch_bounds__(256) void ln_kernel(const float* __restrict__ opre,
                                                 const float* __restrict__ lw,
                                                 const float* __restrict__ lb,
                                                 float* __restrict__ out) {
    __shared__ float red[8];
    const int row = blockIdx.x;
    const int t = threadIdx.x;
    const float* xr = opre + (size_t)row * OUTC;
    float v[4];
    float s = 0.f, s2 = 0.f;
    #pragma unroll
    for (int i = 0; i < 4; ++i) {
        v[i] = xr[t + 256 * i];
        s += v[i];
        s2 += v[i] * v[i];
    }
    #pragma unroll
    for (int o = 32; o; o >>= 1) {
        s += __shfl_down(s, o);
        s2 += __shfl_down(s2, o);
    }
    const int wid = t >> 6;
    if ((t & 63) == 0) { red[wid] = s; red[4 + wid] = s2; }
    __syncthreads();
    if (t == 0) {
        float ts = red[0] + red[1] + red[2] + red[3];
        float ts2 = red[4] + red[5] + red[6] + red[7];
        float mu = ts * (1.f / OUTC);
        float var = ts2 * (1.f / OUTC) - mu * mu;
        red[0] = mu;
        red[1] = rsqrtf(var + 1e-5f);
    }
    __syncthreads();
    const float mu = red[0], rs = red[1];
    #pragma unroll
    for (int i = 0; i < 4; ++i) {
        const int c = t + 256 * i;
        out[(size_t)row * OUTC + c] = (v[i] - mu) * rs * lw[c] + lb[c];
    }
}

// ---------------------------------------------------------------------------
extern "C" void kernel_launch(void* const* d_in, const int* in_sizes, int n_in,
                              void* d_out, int out_size, void* d_ws, size_t ws_size,
                              hipStream_t stream) {
    const float* x1        = (const float*)d_in[0];   // (4,256,32,32) = (1024,1024)
    const float* in_proj_w = (const float*)d_in[1];   // (4096,1024)
    const float* conv_w    = (const float*)d_in[2];   // (2048,1,4)
    const float* conv_b    = (const float*)d_in[3];   // (2048,)
    const float* x_proj_w  = (const float*)d_in[4];   // (96,2048)
    const float* dt_proj_w = (const float*)d_in[5];   // (2048,64)
    const float* dt_proj_b = (const float*)d_in[6];   // (2048,)
    const float* A_log     = (const float*)d_in[7];   // (2048,16)
    const float* Dp        = (const float*)d_in[8];   // (2048,)
    const float* out_proj_w= (const float*)d_in[9];   // (1024,2048)
    const float* ln_w      = (const float*)d_in[10];  // (1024,)
    const float* ln_b      = (const float*)d_in[11];  // (1024,)
    float* out = (float*)d_out;

    float* ws    = (float*)d_ws;
    float* xz    = ws;                       // 1024*4096 = 4,194,304
    float* xs    = xz + 4194304;             // 1024*2048 = 2,097,152
    float* xdbl  = xs + 2097152;             // 1024*96   =    98,304
    float* delta = xdbl + 98304;             // 1024*2048 = 2,097,152
    float* ybuf  = delta + 2097152;          // 1024*2048 = 2,097,152
    float* opre  = ybuf + 2097152;           // 1024*1024 = 1,048,576
    // total ~44.4 MB of float ws

    // 1. in_proj: xz = x @ in_proj_w^T   (1024 x 4096, K=1024)
    gemm_xwt<<<dim3(4096 / 64, 1024 / 64), 256, 0, stream>>>(x1, in_proj_w, xz,
                                                             NROWS, 2 * DINNER, DMODEL);
    // 2. depthwise causal conv + SiLU -> xs
    conv_silu_kernel<<<(NROWS * DINNER) / 256, 256, 0, stream>>>(xz, conv_w, conv_b, xs);
    // 3. x_proj: xdbl = xs @ x_proj_w^T  (1024 x 96, K=2048)
    xproj_kernel<<<dim3(96, NROWS), 64, 0, stream>>>(xs, x_proj_w, xdbl);
    // 4. dt_proj + softplus -> delta (1024 x 2048, K=64)
    dtproj_kernel<<<dim3(DINNER / 256, NROWS), 256, 0, stream>>>(xdbl, dt_proj_w,
                                                                 dt_proj_b, delta);
    // 5. selective scan + gate -> ybuf
    scan_kernel<<<dim3(DINNER / 16, BATCH), 256, 0, stream>>>(delta, xs, xdbl, xz,
                                                              A_log, Dp, ybuf);
    // 6. out_proj: opre = ybuf @ out_proj_w^T (1024 x 1024, K=2048)
    gemm_xwt<<<dim3(1024 / 64, 1024 / 64), 256, 0, stream>>>(ybuf, out_proj_w, opre,
                                                             NROWS, OUTC, DINNER);
    // 7. LayerNorm -> out
    ln_kernel<<<NROWS, 256, 0, stream>>>(opre, ln_w, ln_b, out);
}

// Round 2
// 476.935 us; speedup vs baseline: 1.9645x; 1.9645x over previous
//
#include <hip/hip_runtime.h>
#include <hip/hip_bf16.h>
#include <math.h>

// Problem constants (from reference)
#define BATCH 4
#define SEQL 256          // L = C = 256
#define DMODEL 1024
#define DINNER 2048
#define DSTATE 16
#define DTRANK 64
#define OUTC 1024
#define NROWS (BATCH * SEQL)   // 1024

typedef __attribute__((ext_vector_type(8))) short bf16x8;  // 8 bf16 = 4 VGPRs
typedef __attribute__((ext_vector_type(4))) float f32x4;   // MFMA C/D

// ---------------------------------------------------------------------------
// bf16 MFMA GEMM (m97 structure): C[m,n] = sum_k A[m,k]*B[n,k]  (C = A @ B^T)
// A: (M,K) bf16 row-major, B: (N,K) bf16 row-major, C: (M,N) fp32.
// 128x128 tile, BK=32, 256 threads = 4 waves, each wave a 64x64 sub-tile
// (4x4 grid of 16x16x32 MFMAs). Staging via global_load_lds width=16.
// M,N multiples of 128; K multiple of 32.
// ---------------------------------------------------------------------------
__global__ __launch_bounds__(256) void gemm_mfma(const __hip_bfloat16* __restrict__ A,
                                                 const __hip_bfloat16* __restrict__ B,
                                                 float* __restrict__ C,
                                                 int M, int N, int K) {
    __shared__ __hip_bfloat16 As[128 * 32];   // row-major [128][32]
    __shared__ __hip_bfloat16 Bs[128 * 32];
    const int t  = threadIdx.x;
    const int w  = t >> 6;          // wave 0..3
    const int ln = t & 63;
    const int wm = w >> 1, wn = w & 1;
    const int q  = ln >> 4, lr = ln & 15;
    const int m0 = blockIdx.y * 128;
    const int n0 = blockIdx.x * 128;

    f32x4 acc[4][4] = {};

    const __hip_bfloat16* Ag = A + (size_t)m0 * K;
    const __hip_bfloat16* Bg = B + (size_t)n0 * K;

    for (int k0 = 0; k0 < K; k0 += 32) {
        // Stage 128x32 bf16 tiles: 512 chunks of 16B each; wave w, iter i
        // covers chunks [(i*4+w)*64, +64); lane ln -> chunk base+ln.
        // chunk c -> row r=c>>2, col8=(c&3)*8; LDS elem = c*8 (row-major match).
        #pragma unroll
        for (int i = 0; i < 2; ++i) {
            const int c = (i * 4 + w) * 64 + ln;
            const int r = c >> 2, col = (c & 3) * 8;
            __builtin_amdgcn_global_load_lds(
                (const __attribute__((address_space(1))) void*)(Ag + (size_t)r * K + k0 + col),
                (__attribute__((address_space(3))) void*)(As + (i * 4 + w) * 64 * 8),
                16, 0, 0);
            __builtin_amdgcn_global_load_lds(
                (const __attribute__((address_space(1))) void*)(Bg + (size_t)r * K + k0 + col),
                (__attribute__((address_space(3))) void*)(Bs + (i * 4 + w) * 64 * 8),
                16, 0, 0);
        }
        __syncthreads();
        // A frag: A[m = lane&15][k = quad*8 + j]; B frag: B[n = lane&15][k = quad*8+j]
        bf16x8 af[4], bfr[4];
        #pragma unroll
        for (int i = 0; i < 4; ++i)
            af[i] = *(const bf16x8*)(As + (wm * 64 + i * 16 + lr) * 32 + q * 8);
        #pragma unroll
        for (int j = 0; j < 4; ++j)
            bfr[j] = *(const bf16x8*)(Bs + (wn * 64 + j * 16 + lr) * 32 + q * 8);
        #pragma unroll
        for (int i = 0; i < 4; ++i)
            #pragma unroll
            for (int j = 0; j < 4; ++j)
                acc[i][j] = __builtin_amdgcn_mfma_f32_16x16x32_bf16(af[i], bfr[j], acc[i][j], 0, 0, 0);
        __syncthreads();
    }
    // C/D layout: col = lane&15, row = quad*4 + reg
    #pragma unroll
    for (int i = 0; i < 4; ++i) {
        const int mrow = m0 + wm * 64 + i * 16 + q * 4;
        #pragma unroll
        for (int j = 0; j < 4; ++j) {
            const int ncol = n0 + wn * 64 + j * 16 + lr;
            #pragma unroll
            for (int r = 0; r < 4; ++r)
                C[(size_t)(mrow + r) * N + ncol] = acc[i][j][r];
        }
    }
}

// ---------------------------------------------------------------------------
// fp32 -> bf16 cast
// ---------------------------------------------------------------------------
__global__ void cast_bf16_kernel(const float* __restrict__ in,
                                 __hip_bfloat16* __restrict__ o, int n) {
    int i = blockIdx.x * 256 + threadIdx.x;
    if (i < n) o[i] = __float2bfloat16(in[i]);
}

// x_proj_w (96,2048) -> bf16 padded to (128,2048), rows 96..127 zero
__global__ void cast_pad_xproj(const float* __restrict__ in,
                               __hip_bfloat16* __restrict__ o) {
    int i = blockIdx.x * 256 + threadIdx.x;   // 128*2048
    int e = i >> 11;
    o[i] = __float2bfloat16(e < 96 ? in[i] : 0.f);
}

// ---------------------------------------------------------------------------
// Depthwise causal conv1d (k=4, left pad 3) + bias + SiLU.
// Input: xz (NROWS, 2*DINNER) fp32, uses xs half. Output: xs fp32 AND xsb bf16.
// ---------------------------------------------------------------------------
__global__ void conv_silu_kernel(const float* __restrict__ xz,
                                 const float* __restrict__ conv_w,
                                 const float* __restrict__ conv_b,
                                 float* __restrict__ xs,
                                 __hip_bfloat16* __restrict__ xsb) {
    int idx = blockIdx.x * blockDim.x + threadIdx.x;  // (b*L + l)*DINNER + d
    int d = idx & (DINNER - 1);
    int l = (idx >> 11) & (SEQL - 1);
    int b = idx >> 19;
    const float w0 = conv_w[d * 4 + 0];
    const float w1 = conv_w[d * 4 + 1];
    const float w2 = conv_w[d * 4 + 2];
    const float w3 = conv_w[d * 4 + 3];
    float acc = conv_b[d];
    const size_t base = (size_t)(b * SEQL) * (2 * DINNER) + d;
    if (l >= 3) acc += w0 * xz[base + (size_t)(l - 3) * (2 * DINNER)];
    if (l >= 2) acc += w1 * xz[base + (size_t)(l - 2) * (2 * DINNER)];
    if (l >= 1) acc += w2 * xz[base + (size_t)(l - 1) * (2 * DINNER)];
    acc += w3 * xz[base + (size_t)l * (2 * DINNER)];
    float v = acc / (1.f + __expf(-acc));
    xs[idx] = v;
    xsb[idx] = __float2bfloat16(v);
}

// ---------------------------------------------------------------------------
// dt_proj + softplus: delta[row,d] = softplus(sum_r dt[row,r]*Wd[d,r] + bd[d])
// xdbl has stride 128 now.
// ---------------------------------------------------------------------------
__global__ __launch_bounds__(256) void dtproj_kernel(const float* __restrict__ xdbl,
                                                     const float* __restrict__ Wd,
                                                     const float* __restrict__ bd,
                                                     float* __restrict__ delta) {
    __shared__ float sdt[DTRANK];
    const int row = blockIdx.y;
    const int d = blockIdx.x * 256 + threadIdx.x;
    if (threadIdx.x < DTRANK) sdt[threadIdx.x] = xdbl[row * 128 + threadIdx.x];
    __syncthreads();
    float acc = bd[d];
    const float* w = Wd + (size_t)d * DTRANK;
    #pragma unroll
    for (int r = 0; r < DTRANK; ++r) acc += sdt[r] * w[r];
    float sp = (acc > 20.f) ? acc : log1pf(__expf(acc));
    delta[(size_t)row * DINNER + d] = sp;
}

// ---------------------------------------------------------------------------
// Selective scan, fused with +D*xs and *silu(res). Writes bf16 for out_proj.
// thread = (d_local, n): block 256 = 16 d x 16 n. grid (DINNER/16, B).
// ---------------------------------------------------------------------------
__global__ __launch_bounds__(256) void scan_kernel(const float* __restrict__ delta,
                                                   const float* __restrict__ xs,
                                                   const float* __restrict__ xdbl,
                                                   const float* __restrict__ xz,
                                                   const float* __restrict__ A_log,
                                                   const float* __restrict__ Dp,
                                                   __hip_bfloat16* __restrict__ ybb) {
    const int b = blockIdx.y;
    const int dg = blockIdx.x;          // 0..127
    const int t = threadIdx.x;
    const int dl = t >> 4;              // 0..15
    const int n = t & 15;
    const int d = dg * 16 + dl;
    const float a = -__expf(A_log[d * DSTATE + n]);
    const float Dv = Dp[d];
    float h = 0.f;
    const int rowbase = b * SEQL;
    for (int l = 0; l < SEQL; ++l) {
        const int row = rowbase + l;
        const float dv = delta[(size_t)row * DINNER + d];
        const float xv = xs[(size_t)row * DINNER + d];
        const float bm = xdbl[row * 128 + DTRANK + n];
        const float cm = xdbl[row * 128 + DTRANK + DSTATE + n];
        h = __expf(dv * a) * h + dv * bm * xv;
        float p = h * cm;
        p += __shfl_xor(p, 1);
        p += __shfl_xor(p, 2);
        p += __shfl_xor(p, 4);
        p += __shfl_xor(p, 8);
        if (n == 0) {
            const float r = xz[(size_t)row * (2 * DINNER) + DINNER + d];
            float y = p + Dv * xv;
            y = y * (r / (1.f + __expf(-r)));
            ybb[(size_t)row * DINNER + d] = __float2bfloat16(y);
        }
    }
}

// ---------------------------------------------------------------------------
// LayerNorm over last dim (1024). block per row, 256 threads x 4 elems.
// ---------------------------------------------------------------------------
__global__ __launch_bounds__(256) void ln_kernel(const float* __restrict__ opre,
                                                 const float* __restrict__ lw,
                                                 const float* __restrict__ lb,
                                                 float* __restrict__ out) {
    __shared__ float red[8];
    const int row = blockIdx.x;
    const int t = threadIdx.x;
    const float* xr = opre + (size_t)row * OUTC;
    float v[4];
    float s = 0.f, s2 = 0.f;
    #pragma unroll
    for (int i = 0; i < 4; ++i) {
        v[i] = xr[t + 256 * i];
        s += v[i];
        s2 += v[i] * v[i];
    }
    #pragma unroll
    for (int o = 32; o; o >>= 1) {
        s += __shfl_down(s, o);
        s2 += __shfl_down(s2, o);
    }
    const int wid = t >> 6;
    if ((t & 63) == 0) { red[wid] = s; red[4 + wid] = s2; }
    __syncthreads();
    if (t == 0) {
        float ts = red[0] + red[1] + red[2] + red[3];
        float ts2 = red[4] + red[5] + red[6] + red[7];
        float mu = ts * (1.f / OUTC);
        float var = ts2 * (1.f / OUTC) - mu * mu;
        red[0] = mu;
        red[1] = rsqrtf(var + 1e-5f);
    }
    __syncthreads();
    const float mu = red[0], rs = red[1];
    #pragma unroll
    for (int i = 0; i < 4; ++i) {
        const int c = t + 256 * i;
        out[(size_t)row * OUTC + c] = (v[i] - mu) * rs * lw[c] + lb[c];
    }
}

// ---------------------------------------------------------------------------
extern "C" void kernel_launch(void* const* d_in, const int* in_sizes, int n_in,
                              void* d_out, int out_size, void* d_ws, size_t ws_size,
                              hipStream_t stream) {
    const float* x1        = (const float*)d_in[0];   // (1024,1024)
    const float* in_proj_w = (const float*)d_in[1];   // (4096,1024)
    const float* conv_w    = (const float*)d_in[2];   // (2048,1,4)
    const float* conv_b    = (const float*)d_in[3];   // (2048,)
    const float* x_proj_w  = (const float*)d_in[4];   // (96,2048)
    const float* dt_proj_w = (const float*)d_in[5];   // (2048,64)
    const float* dt_proj_b = (const float*)d_in[6];   // (2048,)
    const float* A_log     = (const float*)d_in[7];   // (2048,16)
    const float* Dp        = (const float*)d_in[8];   // (2048,)
    const float* out_proj_w= (const float*)d_in[9];   // (1024,2048)
    const float* ln_w      = (const float*)d_in[10];  // (1024,)
    const float* ln_b      = (const float*)d_in[11];  // (1024,)
    float* out = (float*)d_out;

    // workspace carve-up (all offsets 256B-aligned)
    char* p = (char*)d_ws;
    __hip_bfloat16* xa  = (__hip_bfloat16*)p; p += (size_t)1024 * 1024 * 2;  // 2 MB
    __hip_bfloat16* wb1 = (__hip_bfloat16*)p; p += (size_t)4096 * 1024 * 2;  // 8 MB
    __hip_bfloat16* wpb = (__hip_bfloat16*)p; p += (size_t)128 * 2048 * 2;   // 0.5 MB
    __hip_bfloat16* wob = (__hip_bfloat16*)p; p += (size_t)1024 * 2048 * 2;  // 4 MB
    __hip_bfloat16* xsb = (__hip_bfloat16*)p; p += (size_t)1024 * 2048 * 2;  // 4 MB
    __hip_bfloat16* ybb = (__hip_bfloat16*)p; p += (size_t)1024 * 2048 * 2;  // 4 MB
    float* xz    = (float*)p; p += (size_t)1024 * 4096 * 4;                  // 16 MB
    float* xs    = (float*)p; p += (size_t)1024 * 2048 * 4;                  // 8 MB
    float* xdbl  = (float*)p; p += (size_t)1024 * 128 * 4;                   // 0.5 MB
    float* delta = (float*)p; p += (size_t)1024 * 2048 * 4;                  // 8 MB
    float* opre  = (float*)p; p += (size_t)1024 * 1024 * 4;                  // 4 MB
    // total ~59 MB

    // casts
    cast_bf16_kernel<<<(1024 * 1024) / 256, 256, 0, stream>>>(x1, xa, 1024 * 1024);
    cast_bf16_kernel<<<(4096 * 1024) / 256, 256, 0, stream>>>(in_proj_w, wb1, 4096 * 1024);
    cast_pad_xproj<<<(128 * 2048) / 256, 256, 0, stream>>>(x_proj_w, wpb);
    cast_bf16_kernel<<<(1024 * 2048) / 256, 256, 0, stream>>>(out_proj_w, wob, 1024 * 2048);

    // 1. in_proj: xz = xa @ wb1^T   (1024 x 4096, K=1024)
    gemm_mfma<<<dim3(4096 / 128, 1024 / 128), 256, 0, stream>>>(xa, wb1, xz,
                                                                NROWS, 2 * DINNER, DMODEL);
    // 2. depthwise causal conv + SiLU -> xs (fp32) + xsb (bf16)
    conv_silu_kernel<<<(NROWS * DINNER) / 256, 256, 0, stream>>>(xz, conv_w, conv_b, xs, xsb);
    // 3. x_proj: xdbl = xsb @ wpb^T  (1024 x 128, K=2048)
    gemm_mfma<<<dim3(128 / 128, 1024 / 128), 256, 0, stream>>>(xsb, wpb, xdbl,
                                                               NROWS, 128, DINNER);
    // 4. dt_proj + softplus -> delta (1024 x 2048, K=64)
    dtproj_kernel<<<dim3(DINNER / 256, NROWS), 256, 0, stream>>>(xdbl, dt_proj_w,
                                                                 dt_proj_b, delta);
    // 5. selective scan + gate -> ybb (bf16)
    scan_kernel<<<dim3(DINNER / 16, BATCH), 256, 0, stream>>>(delta, xs, xdbl, xz,
                                                              A_log, Dp, ybb);
    // 6. out_proj: opre = ybb @ wob^T (1024 x 1024, K=2048)
    gemm_mfma<<<dim3(1024 / 128, 1024 / 128), 256, 0, stream>>>(ybb, wob, opre,
                                                                NROWS, OUTC, DINNER);
    // 7. LayerNorm -> out
    ln_kernel<<<NROWS, 256, 0, stream>>>(opre, ln_w, ln_b, out);
}

// Round 3
// 325.693 us; speedup vs baseline: 2.8768x; 1.4644x over previous
//
#include <hip/hip_runtime.h>
#include <hip/hip_bf16.h>
#include <math.h>

// Problem constants (from reference)
#define BATCH 4
#define SEQL 256          // L = C = 256
#define DMODEL 1024
#define DINNER 2048
#define DSTATE 16
#define DTRANK 64
#define OUTC 1024
#define NROWS (BATCH * SEQL)   // 1024

typedef __attribute__((ext_vector_type(8))) short bf16x8;  // 8 bf16 = 4 VGPRs
typedef __attribute__((ext_vector_type(4))) float f32x4;   // MFMA C/D

// ---------------------------------------------------------------------------
// bf16 MFMA GEMM (m97 structure): C[m,n] = sum_k A[m,k]*B[n,k]  (C = A @ B^T)
// 128x128 tile, BK=32, 256 threads = 4 waves, each wave a 64x64 sub-tile.
// ---------------------------------------------------------------------------
__global__ __launch_bounds__(256) void gemm_mfma(const __hip_bfloat16* __restrict__ A,
                                                 const __hip_bfloat16* __restrict__ B,
                                                 float* __restrict__ C,
                                                 int M, int N, int K) {
    __shared__ __hip_bfloat16 As[128 * 32];   // row-major [128][32]
    __shared__ __hip_bfloat16 Bs[128 * 32];
    const int t  = threadIdx.x;
    const int w  = t >> 6;          // wave 0..3
    const int ln = t & 63;
    const int wm = w >> 1, wn = w & 1;
    const int q  = ln >> 4, lr = ln & 15;
    const int m0 = blockIdx.y * 128;
    const int n0 = blockIdx.x * 128;

    f32x4 acc[4][4] = {};

    const __hip_bfloat16* Ag = A + (size_t)m0 * K;
    const __hip_bfloat16* Bg = B + (size_t)n0 * K;

    for (int k0 = 0; k0 < K; k0 += 32) {
        #pragma unroll
        for (int i = 0; i < 2; ++i) {
            const int c = (i * 4 + w) * 64 + ln;
            const int r = c >> 2, col = (c & 3) * 8;
            __builtin_amdgcn_global_load_lds(
                (const __attribute__((address_space(1))) void*)(Ag + (size_t)r * K + k0 + col),
                (__attribute__((address_space(3))) void*)(As + (i * 4 + w) * 64 * 8),
                16, 0, 0);
            __builtin_amdgcn_global_load_lds(
                (const __attribute__((address_space(1))) void*)(Bg + (size_t)r * K + k0 + col),
                (__attribute__((address_space(3))) void*)(Bs + (i * 4 + w) * 64 * 8),
                16, 0, 0);
        }
        __syncthreads();
        bf16x8 af[4], bfr[4];
        #pragma unroll
        for (int i = 0; i < 4; ++i)
            af[i] = *(const bf16x8*)(As + (wm * 64 + i * 16 + lr) * 32 + q * 8);
        #pragma unroll
        for (int j = 0; j < 4; ++j)
            bfr[j] = *(const bf16x8*)(Bs + (wn * 64 + j * 16 + lr) * 32 + q * 8);
        #pragma unroll
        for (int i = 0; i < 4; ++i)
            #pragma unroll
            for (int j = 0; j < 4; ++j)
                acc[i][j] = __builtin_amdgcn_mfma_f32_16x16x32_bf16(af[i], bfr[j], acc[i][j], 0, 0, 0);
        __syncthreads();
    }
    #pragma unroll
    for (int i = 0; i < 4; ++i) {
        const int mrow = m0 + wm * 64 + i * 16 + q * 4;
        #pragma unroll
        for (int j = 0; j < 4; ++j) {
            const int ncol = n0 + wn * 64 + j * 16 + lr;
            #pragma unroll
            for (int r = 0; r < 4; ++r)
                C[(size_t)(mrow + r) * N + ncol] = acc[i][j][r];
        }
    }
}

// ---------------------------------------------------------------------------
// Fused fp32 -> bf16 casts for all weight/activation inputs.
// Region layout (element index space):
//   [0, 1M)          x1         -> xa
//   [1M, 1M+4M)      in_proj_w  -> wb1
//   [5M, 5M+2M)      out_proj_w -> wob
//   [7M, 7M+256K)    x_proj_w padded (96->128 rows) -> wpb
// ---------------------------------------------------------------------------
#define R0 (1024 * 1024)
#define R1 (R0 + 4096 * 1024)
#define R2 (R1 + 2048 * 1024)
#define R3 (R2 + 128 * 2048)
__global__ void cast_all_kernel(const float* __restrict__ x1,
                                const float* __restrict__ w_in,
                                const float* __restrict__ w_out,
                                const float* __restrict__ w_xp,
                                __hip_bfloat16* __restrict__ xa,
                                __hip_bfloat16* __restrict__ wb1,
                                __hip_bfloat16* __restrict__ wob,
                                __hip_bfloat16* __restrict__ wpb) {
    int i = blockIdx.x * 256 + threadIdx.x;
    if (i < R0) {
        xa[i] = __float2bfloat16(x1[i]);
    } else if (i < R1) {
        int j = i - R0; wb1[j] = __float2bfloat16(w_in[j]);
    } else if (i < R2) {
        int j = i - R1; wob[j] = __float2bfloat16(w_out[j]);
    } else if (i < R3) {
        int j = i - R2; int e = j >> 11;
        wpb[j] = __float2bfloat16(e < 96 ? w_xp[j] : 0.f);
    }
}

// ---------------------------------------------------------------------------
// Depthwise causal conv1d (k=4, left pad 3) + bias + SiLU.
// ---------------------------------------------------------------------------
__global__ void conv_silu_kernel(const float* __restrict__ xz,
                                 const float* __restrict__ conv_w,
                                 const float* __restrict__ conv_b,
                                 float* __restrict__ xs,
                                 __hip_bfloat16* __restrict__ xsb) {
    int idx = blockIdx.x * blockDim.x + threadIdx.x;  // (b*L + l)*DINNER + d
    int d = idx & (DINNER - 1);
    int l = (idx >> 11) & (SEQL - 1);
    int b = idx >> 19;
    const float w0 = conv_w[d * 4 + 0];
    const float w1 = conv_w[d * 4 + 1];
    const float w2 = conv_w[d * 4 + 2];
    const float w3 = conv_w[d * 4 + 3];
    float acc = conv_b[d];
    const size_t base = (size_t)(b * SEQL) * (2 * DINNER) + d;
    if (l >= 3) acc += w0 * xz[base + (size_t)(l - 3) * (2 * DINNER)];
    if (l >= 2) acc += w1 * xz[base + (size_t)(l - 2) * (2 * DINNER)];
    if (l >= 1) acc += w2 * xz[base + (size_t)(l - 1) * (2 * DINNER)];
    acc += w3 * xz[base + (size_t)l * (2 * DINNER)];
    float v = acc / (1.f + __expf(-acc));
    xs[idx] = v;
    xsb[idx] = __float2bfloat16(v);
}

// ---------------------------------------------------------------------------
// dt_proj + softplus (xdbl stride 128)
// ---------------------------------------------------------------------------
__global__ __launch_bounds__(256) void dtproj_kernel(const float* __restrict__ xdbl,
                                                     const float* __restrict__ Wd,
                                                     const float* __restrict__ bd,
                                                     float* __restrict__ delta) {
    __shared__ float sdt[DTRANK];
    const int row = blockIdx.y;
    const int d = blockIdx.x * 256 + threadIdx.x;
    if (threadIdx.x < DTRANK) sdt[threadIdx.x] = xdbl[row * 128 + threadIdx.x];
    __syncthreads();
    float acc = bd[d];
    const float* w = Wd + (size_t)d * DTRANK;
    #pragma unroll
    for (int r = 0; r < DTRANK; ++r) acc += sdt[r] * w[r];
    float sp = (acc > 20.f) ? acc : log1pf(__expf(acc));
    delta[(size_t)row * DINNER + d] = sp;
}

// ---------------------------------------------------------------------------
// 16-lane row sum via DPP row_ror rotations (no DS ops). All 16 lanes of each
// row end with the full row sum.
// ---------------------------------------------------------------------------
__device__ __forceinline__ float row_reduce16(float x) {
    x += __int_as_float(__builtin_amdgcn_update_dpp(0, __float_as_int(x), 0x128, 0xF, 0xF, true));
    x += __int_as_float(__builtin_amdgcn_update_dpp(0, __float_as_int(x), 0x124, 0xF, 0xF, true));
    x += __int_as_float(__builtin_amdgcn_update_dpp(0, __float_as_int(x), 0x122, 0xF, 0xF, true));
    x += __int_as_float(__builtin_amdgcn_update_dpp(0, __float_as_int(x), 0x121, 0xF, 0xF, true));
    return x;
}

// ---------------------------------------------------------------------------
// Selective scan, LDS-staged + register-pipelined, DPP reduction.
// Block = (16 d) x (16 n) = 256 threads; grid (DINNER/16, B).
// Chunks of 64 timesteps; staging precomputes dv, dv*xv, silu(res), D*xv*g.
// ---------------------------------------------------------------------------
#define CHUNK 64
__global__ __launch_bounds__(256) void scan_kernel(const float* __restrict__ delta,
                                                   const float* __restrict__ xs,
                                                   const float* __restrict__ xdbl,
                                                   const float* __restrict__ xz,
                                                   const float* __restrict__ A_log,
                                                   const float* __restrict__ Dp,
                                                   __hip_bfloat16* __restrict__ ybb) {
    __shared__ float sDU[CHUNK][16][2];   // [l][dl][{dv, dv*xv}]
    __shared__ float sBC[CHUNK][16][2];   // [l][n][{B, C}]
    __shared__ float sGW[CHUNK][16][2];   // [l][dl][{g, D*xv*g}]
    const int b = blockIdx.y;
    const int dg = blockIdx.x;
    const int t = threadIdx.x;
    const int dl = t >> 4;              // compute role: d-local
    const int n  = t & 15;              // compute role: state index
    const int d  = dg * 16 + dl;
    const float a = -__expf(A_log[d * DSTATE + n]);
    // staging role: srow = row-within-16-group, scol = column (d or n index)
    const int srow = t >> 4, scol = t & 15;
    const int sd = dg * 16 + scol;
    const float Dstage = Dp[sd];
    const int rowbase = b * SEQL;
    float h = 0.f;

    float rD[4], rX[4], rR[4], rB[4], rC[4];

    auto issue_loads = [&](int l0) {
        #pragma unroll
        for (int i = 0; i < 4; ++i) {
            const int row = rowbase + l0 + i * 16 + srow;
            rD[i] = delta[(size_t)row * DINNER + sd];
            rX[i] = xs[(size_t)row * DINNER + sd];
            rR[i] = xz[(size_t)row * (2 * DINNER) + DINNER + sd];
            rB[i] = xdbl[row * 128 + 64 + scol];
            rC[i] = xdbl[row * 128 + 80 + scol];
        }
    };
    auto write_lds = [&]() {
        #pragma unroll
        for (int i = 0; i < 4; ++i) {
            const int row = i * 16 + srow;
            const float dv = rD[i], xv = rX[i], r = rR[i];
            const float g = r / (1.f + __expf(-r));
            sDU[row][scol][0] = dv;
            sDU[row][scol][1] = dv * xv;
            sGW[row][scol][0] = g;
            sGW[row][scol][1] = Dstage * xv * g;
            sBC[row][scol][0] = rB[i];
            sBC[row][scol][1] = rC[i];
        }
    };

    issue_loads(0);
    write_lds();
    __syncthreads();
    for (int c = 0; c < SEQL / CHUNK; ++c) {
        if (c + 1 < SEQL / CHUNK) issue_loads((c + 1) * CHUNK);
        const int l0 = c * CHUNK;
        #pragma unroll 16
        for (int l = 0; l < CHUNK; ++l) {
            const float dv = sDU[l][dl][0];
            const float u  = sDU[l][dl][1];
            const float bm = sBC[l][n][0];
            const float cm = sBC[l][n][1];
            const float e = __expf(dv * a);
            h = e * h + u * bm;
            float p = row_reduce16(h * cm);
            const float g  = sGW[l][dl][0];
            const float wg = sGW[l][dl][1];
            if (n == 0) {
                const float y = p * g + wg;
                ybb[(size_t)(rowbase + l0 + l) * DINNER + d] = __float2bfloat16(y);
            }
        }
        __syncthreads();
        if (c + 1 < SEQL / CHUNK) {
            write_lds();
        }
        __syncthreads();
    }
}

// ---------------------------------------------------------------------------
// LayerNorm over last dim (1024). block per row, 256 threads x 4 elems.
// ---------------------------------------------------------------------------
__global__ __launch_bounds__(256) void ln_kernel(const float* __restrict__ opre,
                                                 const float* __restrict__ lw,
                                                 const float* __restrict__ lb,
                                                 float* __restrict__ out) {
    __shared__ float red[8];
    const int row = blockIdx.x;
    const int t = threadIdx.x;
    const float* xr = opre + (size_t)row * OUTC;
    float v[4];
    float s = 0.f, s2 = 0.f;
    #pragma unroll
    for (int i = 0; i < 4; ++i) {
        v[i] = xr[t + 256 * i];
        s += v[i];
        s2 += v[i] * v[i];
    }
    #pragma unroll
    for (int o = 32; o; o >>= 1) {
        s += __shfl_down(s, o);
        s2 += __shfl_down(s2, o);
    }
    const int wid = t >> 6;
    if ((t & 63) == 0) { red[wid] = s; red[4 + wid] = s2; }
    __syncthreads();
    if (t == 0) {
        float ts = red[0] + red[1] + red[2] + red[3];
        float ts2 = red[4] + red[5] + red[6] + red[7];
        float mu = ts * (1.f / OUTC);
        float var = ts2 * (1.f / OUTC) - mu * mu;
        red[0] = mu;
        red[1] = rsqrtf(var + 1e-5f);
    }
    __syncthreads();
    const float mu = red[0], rs = red[1];
    #pragma unroll
    for (int i = 0; i < 4; ++i) {
        const int c = t + 256 * i;
        out[(size_t)row * OUTC + c] = (v[i] - mu) * rs * lw[c] + lb[c];
    }
}

// ---------------------------------------------------------------------------
extern "C" void kernel_launch(void* const* d_in, const int* in_sizes, int n_in,
                              void* d_out, int out_size, void* d_ws, size_t ws_size,
                              hipStream_t stream) {
    const float* x1        = (const float*)d_in[0];   // (1024,1024)
    const float* in_proj_w = (const float*)d_in[1];   // (4096,1024)
    const float* conv_w    = (const float*)d_in[2];   // (2048,1,4)
    const float* conv_b    = (const float*)d_in[3];   // (2048,)
    const float* x_proj_w  = (const float*)d_in[4];   // (96,2048)
    const float* dt_proj_w = (const float*)d_in[5];   // (2048,64)
    const float* dt_proj_b = (const float*)d_in[6];   // (2048,)
    const float* A_log     = (const float*)d_in[7];   // (2048,16)
    const float* Dp        = (const float*)d_in[8];   // (2048,)
    const float* out_proj_w= (const float*)d_in[9];   // (1024,2048)
    const float* ln_w      = (const float*)d_in[10];  // (1024,)
    const float* ln_b      = (const float*)d_in[11];  // (1024,)
    float* out = (float*)d_out;

    // workspace carve-up (all offsets 256B-aligned)
    char* p = (char*)d_ws;
    __hip_bfloat16* xa  = (__hip_bfloat16*)p; p += (size_t)1024 * 1024 * 2;  // 2 MB
    __hip_bfloat16* wb1 = (__hip_bfloat16*)p; p += (size_t)4096 * 1024 * 2;  // 8 MB
    __hip_bfloat16* wpb = (__hip_bfloat16*)p; p += (size_t)128 * 2048 * 2;   // 0.5 MB
    __hip_bfloat16* wob = (__hip_bfloat16*)p; p += (size_t)1024 * 2048 * 2;  // 4 MB
    __hip_bfloat16* xsb = (__hip_bfloat16*)p; p += (size_t)1024 * 2048 * 2;  // 4 MB
    __hip_bfloat16* ybb = (__hip_bfloat16*)p; p += (size_t)1024 * 2048 * 2;  // 4 MB
    float* xz    = (float*)p; p += (size_t)1024 * 4096 * 4;                  // 16 MB
    float* xs    = (float*)p; p += (size_t)1024 * 2048 * 4;                  // 8 MB
    float* xdbl  = (float*)p; p += (size_t)1024 * 128 * 4;                   // 0.5 MB
    float* delta = (float*)p; p += (size_t)1024 * 2048 * 4;                  // 8 MB
    float* opre  = (float*)p; p += (size_t)1024 * 1024 * 4;                  // 4 MB

    // 0. fused bf16 casts (x1, in_proj_w, out_proj_w, padded x_proj_w)
    cast_all_kernel<<<(R3 + 255) / 256, 256, 0, stream>>>(x1, in_proj_w, out_proj_w,
                                                          x_proj_w, xa, wb1, wob, wpb);
    // 1. in_proj: xz = xa @ wb1^T   (1024 x 4096, K=1024)
    gemm_mfma<<<dim3(4096 / 128, 1024 / 128), 256, 0, stream>>>(xa, wb1, xz,
                                                                NROWS, 2 * DINNER, DMODEL);
    // 2. depthwise causal conv + SiLU -> xs (fp32) + xsb (bf16)
    conv_silu_kernel<<<(NROWS * DINNER) / 256, 256, 0, stream>>>(xz, conv_w, conv_b, xs, xsb);
    // 3. x_proj: xdbl = xsb @ wpb^T  (1024 x 128, K=2048)
    gemm_mfma<<<dim3(128 / 128, 1024 / 128), 256, 0, stream>>>(xsb, wpb, xdbl,
                                                               NROWS, 128, DINNER);
    // 4. dt_proj + softplus -> delta (1024 x 2048, K=64)
    dtproj_kernel<<<dim3(DINNER / 256, NROWS), 256, 0, stream>>>(xdbl, dt_proj_w,
                                                                 dt_proj_b, delta);
    // 5. selective scan + gate -> ybb (bf16)
    scan_kernel<<<dim3(DINNER / 16, BATCH), 256, 0, stream>>>(delta, xs, xdbl, xz,
                                                              A_log, Dp, ybb);
    // 6. out_proj: opre = ybb @ wob^T (1024 x 1024, K=2048)
    gemm_mfma<<<dim3(1024 / 128, 1024 / 128), 256, 0, stream>>>(ybb, wob, opre,
                                                                NROWS, OUTC, DINNER);
    // 7. LayerNorm -> out
    ln_kernel<<<NROWS, 256, 0, stream>>>(opre, ln_w, ln_b, out);
}

// Round 4
// 228.984 us; speedup vs baseline: 4.0917x; 1.4223x over previous
//
#include <hip/hip_runtime.h>
#include <hip/hip_bf16.h>
#include <math.h>

// Problem constants (from reference)
#define BATCH 4
#define SEQL 256          // L = C = 256
#define DMODEL 1024
#define DINNER 2048
#define DSTATE 16
#define DTRANK 64
#define OUTC 1024
#define NROWS (BATCH * SEQL)   // 1024

typedef __attribute__((ext_vector_type(8))) short bf16x8;  // 8 bf16 = 4 VGPRs
typedef __attribute__((ext_vector_type(4))) float f32x4;   // MFMA C/D

// ---------------------------------------------------------------------------
// bf16 MFMA GEMM (m97 structure): C = A @ B^T, with optional split-K over
// blockIdx.z: each z-slice computes a partial over K/gridDim.z and writes to
// C + z*M*N. A: (M,lda-strided) bf16, B: (N,ldb) bf16, C slices: (M,N) fp32.
// 128x128 tile, BK=32, 256 threads = 4 waves, each wave a 64x64 sub-tile.
// ---------------------------------------------------------------------------
__global__ __launch_bounds__(256) void gemm_mfma(const __hip_bfloat16* __restrict__ A,
                                                 const __hip_bfloat16* __restrict__ B,
                                                 float* __restrict__ C,
                                                 int M, int N, int K,
                                                 int lda, int ldb) {
    __shared__ __hip_bfloat16 As[128 * 32];   // row-major [128][32]
    __shared__ __hip_bfloat16 Bs[128 * 32];
    const int t  = threadIdx.x;
    const int w  = t >> 6;          // wave 0..3
    const int ln = t & 63;
    const int wm = w >> 1, wn = w & 1;
    const int q  = ln >> 4, lr = ln & 15;
    const int m0 = blockIdx.y * 128;
    const int n0 = blockIdx.x * 128;
    const int Kpart = K / gridDim.z;
    const int kbase = blockIdx.z * Kpart;

    f32x4 acc[4][4] = {};

    const __hip_bfloat16* Ag = A + (size_t)m0 * lda + kbase;
    const __hip_bfloat16* Bg = B + (size_t)n0 * ldb + kbase;

    for (int k0 = 0; k0 < Kpart; k0 += 32) {
        #pragma unroll
        for (int i = 0; i < 2; ++i) {
            const int c = (i * 4 + w) * 64 + ln;
            const int r = c >> 2, col = (c & 3) * 8;
            __builtin_amdgcn_global_load_lds(
                (const __attribute__((address_space(1))) void*)(Ag + (size_t)r * lda + k0 + col),
                (__attribute__((address_space(3))) void*)(As + (i * 4 + w) * 64 * 8),
                16, 0, 0);
            __builtin_amdgcn_global_load_lds(
                (const __attribute__((address_space(1))) void*)(Bg + (size_t)r * ldb + k0 + col),
                (__attribute__((address_space(3))) void*)(Bs + (i * 4 + w) * 64 * 8),
                16, 0, 0);
        }
        __syncthreads();
        bf16x8 af[4], bfr[4];
        #pragma unroll
        for (int i = 0; i < 4; ++i)
            af[i] = *(const bf16x8*)(As + (wm * 64 + i * 16 + lr) * 32 + q * 8);
        #pragma unroll
        for (int j = 0; j < 4; ++j)
            bfr[j] = *(const bf16x8*)(Bs + (wn * 64 + j * 16 + lr) * 32 + q * 8);
        #pragma unroll
        for (int i = 0; i < 4; ++i)
            #pragma unroll
            for (int j = 0; j < 4; ++j)
                acc[i][j] = __builtin_amdgcn_mfma_f32_16x16x32_bf16(af[i], bfr[j], acc[i][j], 0, 0, 0);
        __syncthreads();
    }
    float* Cz = C + (size_t)blockIdx.z * M * N;
    #pragma unroll
    for (int i = 0; i < 4; ++i) {
        const int mrow = m0 + wm * 64 + i * 16 + q * 4;
        #pragma unroll
        for (int j = 0; j < 4; ++j) {
            const int ncol = n0 + wn * 64 + j * 16 + lr;
            #pragma unroll
            for (int r = 0; r < 4; ++r)
                Cz[(size_t)(mrow + r) * N + ncol] = acc[i][j][r];
        }
    }
}

// ---------------------------------------------------------------------------
// dt_proj as MFMA GEMM with fused bias + softplus epilogue.
// delta[m,n] = softplus(sum_k dtb[m,k]*Wdb[n,k] + bd[n])
// M=1024, N=2048, K=64. dtb lda=128 (xdblb stride), Wdb ldb=64.
// ---------------------------------------------------------------------------
__global__ __launch_bounds__(256) void gemm_dtsp(const __hip_bfloat16* __restrict__ A,
                                                 const __hip_bfloat16* __restrict__ B,
                                                 const float* __restrict__ bd,
                                                 float* __restrict__ delta) {
    __shared__ __hip_bfloat16 As[128 * 32];
    __shared__ __hip_bfloat16 Bs[128 * 32];
    const int t  = threadIdx.x;
    const int w  = t >> 6;
    const int ln = t & 63;
    const int wm = w >> 1, wn = w & 1;
    const int q  = ln >> 4, lr = ln & 15;
    const int m0 = blockIdx.y * 128;
    const int n0 = blockIdx.x * 128;
    const int lda = 128, ldb = 64, N = 2048;

    f32x4 acc[4][4] = {};
    const __hip_bfloat16* Ag = A + (size_t)m0 * lda;
    const __hip_bfloat16* Bg = B + (size_t)n0 * ldb;

    for (int k0 = 0; k0 < 64; k0 += 32) {
        #pragma unroll
        for (int i = 0; i < 2; ++i) {
            const int c = (i * 4 + w) * 64 + ln;
            const int r = c >> 2, col = (c & 3) * 8;
            __builtin_amdgcn_global_load_lds(
                (const __attribute__((address_space(1))) void*)(Ag + (size_t)r * lda + k0 + col),
                (__attribute__((address_space(3))) void*)(As + (i * 4 + w) * 64 * 8),
                16, 0, 0);
            __builtin_amdgcn_global_load_lds(
                (const __attribute__((address_space(1))) void*)(Bg + (size_t)r * ldb + k0 + col),
                (__attribute__((address_space(3))) void*)(Bs + (i * 4 + w) * 64 * 8),
                16, 0, 0);
        }
        __syncthreads();
        bf16x8 af[4], bfr[4];
        #pragma unroll
        for (int i = 0; i < 4; ++i)
            af[i] = *(const bf16x8*)(As + (wm * 64 + i * 16 + lr) * 32 + q * 8);
        #pragma unroll
        for (int j = 0; j < 4; ++j)
            bfr[j] = *(const bf16x8*)(Bs + (wn * 64 + j * 16 + lr) * 32 + q * 8);
        #pragma unroll
        for (int i = 0; i < 4; ++i)
            #pragma unroll
            for (int j = 0; j < 4; ++j)
                acc[i][j] = __builtin_amdgcn_mfma_f32_16x16x32_bf16(af[i], bfr[j], acc[i][j], 0, 0, 0);
        __syncthreads();
    }
    #pragma unroll
    for (int i = 0; i < 4; ++i) {
        const int mrow = m0 + wm * 64 + i * 16 + q * 4;
        #pragma unroll
        for (int j = 0; j < 4; ++j) {
            const int ncol = n0 + wn * 64 + j * 16 + lr;
            const float bias = bd[ncol];
            #pragma unroll
            for (int r = 0; r < 4; ++r) {
                float v = acc[i][j][r] + bias;
                float sp = (v > 20.f) ? v : log1pf(__expf(v));
                delta[(size_t)(mrow + r) * N + ncol] = sp;
            }
        }
    }
}

// ---------------------------------------------------------------------------
// Reduce 8 split-K partials of x_proj -> xdbl fp32 (1024x128) + xdblb bf16.
// ---------------------------------------------------------------------------
__global__ void xdbl_reduce_kernel(const float* __restrict__ part,
                                   float* __restrict__ xdbl,
                                   __hip_bfloat16* __restrict__ xdblb) {
    const int i = blockIdx.x * 256 + threadIdx.x;   // 1024*128
    float s = 0.f;
    #pragma unroll
    for (int z = 0; z < 8; ++z) s += part[(size_t)z * (1024 * 128) + i];
    xdbl[i] = s;
    xdblb[i] = __float2bfloat16(s);
}

// ---------------------------------------------------------------------------
// Fused fp32 -> bf16 casts for all weight/activation inputs.
//   [0, 1M)          x1         -> xa
//   [1M, 5M)         in_proj_w  -> wb1
//   [5M, 7M)         out_proj_w -> wob
//   [7M, 7M+256K)    x_proj_w padded (96->128 rows) -> wpb
//   [.., +128K)      dt_proj_w  -> wdb
// ---------------------------------------------------------------------------
#define R0 (1024 * 1024)
#define R1 (R0 + 4096 * 1024)
#define R2 (R1 + 2048 * 1024)
#define R3 (R2 + 128 * 2048)
#define R4 (R3 + 2048 * 64)
__global__ void cast_all_kernel(const float* __restrict__ x1,
                                const float* __restrict__ w_in,
                                const float* __restrict__ w_out,
                                const float* __restrict__ w_xp,
                                const float* __restrict__ w_dt,
                                __hip_bfloat16* __restrict__ xa,
                                __hip_bfloat16* __restrict__ wb1,
                                __hip_bfloat16* __restrict__ wob,
                                __hip_bfloat16* __restrict__ wpb,
                                __hip_bfloat16* __restrict__ wdb) {
    int i = blockIdx.x * 256 + threadIdx.x;
    if (i < R0) {
        xa[i] = __float2bfloat16(x1[i]);
    } else if (i < R1) {
        int j = i - R0; wb1[j] = __float2bfloat16(w_in[j]);
    } else if (i < R2) {
        int j = i - R1; wob[j] = __float2bfloat16(w_out[j]);
    } else if (i < R3) {
        int j = i - R2; int e = j >> 11;
        wpb[j] = __float2bfloat16(e < 96 ? w_xp[j] : 0.f);
    } else if (i < R4) {
        int j = i - R3; wdb[j] = __float2bfloat16(w_dt[j]);
    }
}

// ---------------------------------------------------------------------------
// Depthwise causal conv1d (k=4, left pad 3) + bias + SiLU.
// ---------------------------------------------------------------------------
__global__ void conv_silu_kernel(const float* __restrict__ xz,
                                 const float* __restrict__ conv_w,
                                 const float* __restrict__ conv_b,
                                 float* __restrict__ xs,
                                 __hip_bfloat16* __restrict__ xsb) {
    int idx = blockIdx.x * blockDim.x + threadIdx.x;  // (b*L + l)*DINNER + d
    int d = idx & (DINNER - 1);
    int l = (idx >> 11) & (SEQL - 1);
    int b = idx >> 19;
    const float w0 = conv_w[d * 4 + 0];
    const float w1 = conv_w[d * 4 + 1];
    const float w2 = conv_w[d * 4 + 2];
    const float w3 = conv_w[d * 4 + 3];
    float acc = conv_b[d];
    const size_t base = (size_t)(b * SEQL) * (2 * DINNER) + d;
    if (l >= 3) acc += w0 * xz[base + (size_t)(l - 3) * (2 * DINNER)];
    if (l >= 2) acc += w1 * xz[base + (size_t)(l - 2) * (2 * DINNER)];
    if (l >= 1) acc += w2 * xz[base + (size_t)(l - 1) * (2 * DINNER)];
    acc += w3 * xz[base + (size_t)l * (2 * DINNER)];
    float v = acc / (1.f + __expf(-acc));
    xs[idx] = v;
    xsb[idx] = __float2bfloat16(v);
}

// ---------------------------------------------------------------------------
// 16-lane row sum via DPP row_ror rotations (no DS ops).
// ---------------------------------------------------------------------------
__device__ __forceinline__ float row_reduce16(float x) {
    x += __int_as_float(__builtin_amdgcn_update_dpp(0, __float_as_int(x), 0x128, 0xF, 0xF, true));
    x += __int_as_float(__builtin_amdgcn_update_dpp(0, __float_as_int(x), 0x124, 0xF, 0xF, true));
    x += __int_as_float(__builtin_amdgcn_update_dpp(0, __float_as_int(x), 0x122, 0xF, 0xF, true));
    x += __int_as_float(__builtin_amdgcn_update_dpp(0, __float_as_int(x), 0x121, 0xF, 0xF, true));
    return x;
}

// ---------------------------------------------------------------------------
// Selective scan, LDS-staged + register-pipelined, DPP reduction.
// ---------------------------------------------------------------------------
#define CHUNK 64
__global__ __launch_bounds__(256) void scan_kernel(const float* __restrict__ delta,
                                                   const float* __restrict__ xs,
                                                   const float* __restrict__ xdbl,
                                                   const float* __restrict__ xz,
                                                   const float* __restrict__ A_log,
                                                   const float* __restrict__ Dp,
                                                   __hip_bfloat16* __restrict__ ybb) {
    __shared__ float sDU[CHUNK][16][2];   // [l][dl][{dv, dv*xv}]
    __shared__ float sBC[CHUNK][16][2];   // [l][n][{B, C}]
    __shared__ float sGW[CHUNK][16][2];   // [l][dl][{g, D*xv*g}]
    const int b = blockIdx.y;
    const int dg = blockIdx.x;
    const int t = threadIdx.x;
    const int dl = t >> 4;
    const int n  = t & 15;
    const int d  = dg * 16 + dl;
    const float a = -__expf(A_log[d * DSTATE + n]);
    const int srow = t >> 4, scol = t & 15;
    const int sd = dg * 16 + scol;
    const float Dstage = Dp[sd];
    const int rowbase = b * SEQL;
    float h = 0.f;

    float rD[4], rX[4], rR[4], rB[4], rC[4];

    auto issue_loads = [&](int l0) {
        #pragma unroll
        for (int i = 0; i < 4; ++i) {
            const int row = rowbase + l0 + i * 16 + srow;
            rD[i] = delta[(size_t)row * DINNER + sd];
            rX[i] = xs[(size_t)row * DINNER + sd];
            rR[i] = xz[(size_t)row * (2 * DINNER) + DINNER + sd];
            rB[i] = xdbl[row * 128 + 64 + scol];
            rC[i] = xdbl[row * 128 + 80 + scol];
        }
    };
    auto write_lds = [&]() {
        #pragma unroll
        for (int i = 0; i < 4; ++i) {
            const int row = i * 16 + srow;
            const float dv = rD[i], xv = rX[i], r = rR[i];
            const float g = r / (1.f + __expf(-r));
            sDU[row][scol][0] = dv;
            sDU[row][scol][1] = dv * xv;
            sGW[row][scol][0] = g;
            sGW[row][scol][1] = Dstage * xv * g;
            sBC[row][scol][0] = rB[i];
            sBC[row][scol][1] = rC[i];
        }
    };

    issue_loads(0);
    write_lds();
    __syncthreads();
    for (int c = 0; c < SEQL / CHUNK; ++c) {
        if (c + 1 < SEQL / CHUNK) issue_loads((c + 1) * CHUNK);
        const int l0 = c * CHUNK;
        #pragma unroll 16
        for (int l = 0; l < CHUNK; ++l) {
            const float dv = sDU[l][dl][0];
            const float u  = sDU[l][dl][1];
            const float bm = sBC[l][n][0];
            const float cm = sBC[l][n][1];
            const float e = __expf(dv * a);
            h = e * h + u * bm;
            float p = row_reduce16(h * cm);
            const float g  = sGW[l][dl][0];
            const float wg = sGW[l][dl][1];
            if (n == 0) {
                const float y = p * g + wg;
                ybb[(size_t)(rowbase + l0 + l) * DINNER + d] = __float2bfloat16(y);
            }
        }
        __syncthreads();
        if (c + 1 < SEQL / CHUNK) {
            write_lds();
        }
        __syncthreads();
    }
}

// ---------------------------------------------------------------------------
// LayerNorm over last dim (1024), fused 4-way split-K reduce of out_proj
// partials. block per row, 256 threads x 4 elems.
// ---------------------------------------------------------------------------
__global__ __launch_bounds__(256) void ln_kernel(const float* __restrict__ opart,
                                                 const float* __restrict__ lw,
                                                 const float* __restrict__ lb,
                                                 float* __restrict__ out) {
    __shared__ float red[8];
    const int row = blockIdx.x;
    const int t = threadIdx.x;
    float v[4];
    float s = 0.f, s2 = 0.f;
    #pragma unroll
    for (int i = 0; i < 4; ++i) {
        const int c = t + 256 * i;
        float acc = 0.f;
        #pragma unroll
        for (int z = 0; z < 4; ++z)
            acc += opart[(size_t)z * (1024 * 1024) + (size_t)row * OUTC + c];
        v[i] = acc;
        s += acc;
        s2 += acc * acc;
    }
    #pragma unroll
    for (int o = 32; o; o >>= 1) {
        s += __shfl_down(s, o);
        s2 += __shfl_down(s2, o);
    }
    const int wid = t >> 6;
    if ((t & 63) == 0) { red[wid] = s; red[4 + wid] = s2; }
    __syncthreads();
    if (t == 0) {
        float ts = red[0] + red[1] + red[2] + red[3];
        float ts2 = red[4] + red[5] + red[6] + red[7];
        float mu = ts * (1.f / OUTC);
        float var = ts2 * (1.f / OUTC) - mu * mu;
        red[0] = mu;
        red[1] = rsqrtf(var + 1e-5f);
    }
    __syncthreads();
    const float mu = red[0], rs = red[1];
    #pragma unroll
    for (int i = 0; i < 4; ++i) {
        const int c = t + 256 * i;
        out[(size_t)row * OUTC + c] = (v[i] - mu) * rs * lw[c] + lb[c];
    }
}

// ---------------------------------------------------------------------------
extern "C" void kernel_launch(void* const* d_in, const int* in_sizes, int n_in,
                              void* d_out, int out_size, void* d_ws, size_t ws_size,
                              hipStream_t stream) {
    const float* x1        = (const float*)d_in[0];   // (1024,1024)
    const float* in_proj_w = (const float*)d_in[1];   // (4096,1024)
    const float* conv_w    = (const float*)d_in[2];   // (2048,1,4)
    const float* conv_b    = (const float*)d_in[3];   // (2048,)
    const float* x_proj_w  = (const float*)d_in[4];   // (96,2048)
    const float* dt_proj_w = (const float*)d_in[5];   // (2048,64)
    const float* dt_proj_b = (const float*)d_in[6];   // (2048,)
    const float* A_log     = (const float*)d_in[7];   // (2048,16)
    const float* Dp        = (const float*)d_in[8];   // (2048,)
    const float* out_proj_w= (const float*)d_in[9];   // (1024,2048)
    const float* ln_w      = (const float*)d_in[10];  // (1024,)
    const float* ln_b      = (const float*)d_in[11];  // (1024,)
    float* out = (float*)d_out;

    // workspace carve-up
    char* p = (char*)d_ws;
    __hip_bfloat16* xa    = (__hip_bfloat16*)p; p += (size_t)1024 * 1024 * 2;  // 2 MB
    __hip_bfloat16* wb1   = (__hip_bfloat16*)p; p += (size_t)4096 * 1024 * 2;  // 8 MB
    __hip_bfloat16* wpb   = (__hip_bfloat16*)p; p += (size_t)128 * 2048 * 2;   // 0.5 MB
    __hip_bfloat16* wob   = (__hip_bfloat16*)p; p += (size_t)1024 * 2048 * 2;  // 4 MB
    __hip_bfloat16* wdb   = (__hip_bfloat16*)p; p += (size_t)2048 * 64 * 2;    // 0.25 MB
    __hip_bfloat16* xsb   = (__hip_bfloat16*)p; p += (size_t)1024 * 2048 * 2;  // 4 MB
    __hip_bfloat16* ybb   = (__hip_bfloat16*)p; p += (size_t)1024 * 2048 * 2;  // 4 MB
    __hip_bfloat16* xdblb = (__hip_bfloat16*)p; p += (size_t)1024 * 128 * 2;   // 0.25 MB
    float* xz    = (float*)p; p += (size_t)1024 * 4096 * 4;                    // 16 MB
    float* xs    = (float*)p; p += (size_t)1024 * 2048 * 4;                    // 8 MB
    float* xdbl  = (float*)p; p += (size_t)1024 * 128 * 4;                     // 0.5 MB
    float* xpart = (float*)p; p += (size_t)8 * 1024 * 128 * 4;                 // 4 MB
    float* delta = (float*)p; p += (size_t)1024 * 2048 * 4;                    // 8 MB
    // out_proj partials (16 MB) alias xz: scan (last reader of xz) precedes
    // out_proj in stream order.
    float* opart = xz;

    // 0. fused bf16 casts
    cast_all_kernel<<<(R4 + 255) / 256, 256, 0, stream>>>(x1, in_proj_w, out_proj_w,
                                                          x_proj_w, dt_proj_w,
                                                          xa, wb1, wob, wpb, wdb);
    // 1. in_proj: xz = xa @ wb1^T   (1024 x 4096, K=1024)
    gemm_mfma<<<dim3(32, 8, 1), 256, 0, stream>>>(xa, wb1, xz,
                                                  NROWS, 2 * DINNER, DMODEL, DMODEL, DMODEL);
    // 2. depthwise causal conv + SiLU -> xs (fp32) + xsb (bf16)
    conv_silu_kernel<<<(NROWS * DINNER) / 256, 256, 0, stream>>>(xz, conv_w, conv_b, xs, xsb);
    // 3. x_proj: xpart[z] = xsb @ wpb^T partials (1024 x 128, K=2048, split 8)
    gemm_mfma<<<dim3(1, 8, 8), 256, 0, stream>>>(xsb, wpb, xpart,
                                                 NROWS, 128, DINNER, DINNER, DINNER);
    xdbl_reduce_kernel<<<(1024 * 128) / 256, 256, 0, stream>>>(xpart, xdbl, xdblb);
    // 4. dt_proj + softplus -> delta (MFMA, K=64)
    gemm_dtsp<<<dim3(16, 8), 256, 0, stream>>>(xdblb, wdb, dt_proj_b, delta);
    // 5. selective scan + gate -> ybb (bf16)
    scan_kernel<<<dim3(DINNER / 16, BATCH), 256, 0, stream>>>(delta, xs, xdbl, xz,
                                                              A_log, Dp, ybb);
    // 6. out_proj partials: opart[z] = ybb @ wob^T (1024 x 1024, K=2048, split 4)
    gemm_mfma<<<dim3(8, 8, 4), 256, 0, stream>>>(ybb, wob, opart,
                                                 NROWS, OUTC, DINNER, DINNER, DINNER);
    // 7. LayerNorm (+ split-K reduce) -> out
    ln_kernel<<<NROWS, 256, 0, stream>>>(opart, ln_w, ln_b, out);
}